// Round 1
// baseline (436.432 us; speedup 1.0000x reference)
//
#include <hip/hip_runtime.h>
#include <math.h>

#define MUL 32
#define NATTR 4
#define NBASIS 10
#define HID 64
#define OUT_DIM 16
#define NGRAPH 8

#define PI_F 3.14159265358979323846f
#define SQRT3_F 1.7320508075688772f
#define INV_SQRT3_F 0.5773502691896258f
#define INV_SQRT10_F 0.31622776601683794f
#define INV_SQRTNN_F 0.17677669529663687f   // 1/sqrt(32)
#define NORM128_F 0.08838834764831845f      // 1/sqrt(128)
#define NORM256_F 0.0625f                   // 1/sqrt(256)
#define C_S_F 0.3826834323650898f           // sin(pi/8)
#define C_X_F 0.9238795325112867f           // cos(pi/8)
#define CSTEP_F (4.0f/9.0f)                 // linspace(0,4,10) step

#define HS 72    // bf16 row stride (shorts): 64 + 8 pad -> 144B, 16B-aligned

typedef __attribute__((ext_vector_type(8))) short bf16x8;
typedef __attribute__((ext_vector_type(4))) float f32x4;

__device__ inline unsigned short f2bf(float x) {
    unsigned u = __float_as_uint(x);
    u += 0x7FFF + ((u >> 16) & 1);          // round-to-nearest-even
    return (unsigned short)(u >> 16);
}
__device__ inline float bf2f(unsigned short h) {
    return __uint_as_float(((unsigned)h) << 16);
}

// ---------------------------------------------------------------- init s,v
__global__ void init_sv(const float* __restrict__ x,
                        float* __restrict__ s, float* __restrict__ v, int N) {
    int i = blockIdx.x * 256 + threadIdx.x;
    if (i >= N * 128) return;
    int n = i >> 7, c = i & 127;
    float val = x[i];
    if (c < 32) s[n * 32 + c] = val;
    else        v[n * 96 + (c - 32)] = val;
}

// ---------------------------------------------------------------- weight setup
__global__ void setup_weights(const float* __restrict__ Wfc1g,
                              const float* __restrict__ Wfc2,
                              const float* __restrict__ Wsc0, const float* __restrict__ Wl10,
                              const float* __restrict__ Wsc1, const float* __restrict__ Wl11,
                              const float* __restrict__ Wl20, const float* __restrict__ Wl21,
                              unsigned short* __restrict__ wfc1f,
                              unsigned short* __restrict__ wfc2f,
                              float* __restrict__ Wfp, unsigned* __restrict__ Wupk) {
    int i = blockIdx.x * 256 + threadIdx.x;
    if (i < 4096) {
        int l = i >> 11, r = i & 2047;
        int nt = r >> 9, lanej = r & 511;
        int lane = lanej >> 3, j = lanej & 7;
        int m16 = lane & 15, quad = lane >> 4;
        int k = quad * 8 + j, n = nt * 16 + m16;
        float val = (k < NBASIS) ? Wfc1g[l * 640 + k * 64 + n] : 0.f;
        wfc1f[i] = f2bf(val);
    } else if (i < 20480) {
        int i2 = i - 4096;
        int l = i2 >> 13, r = i2 & 8191;
        int f = r >> 9, lanej = r & 511;
        int lane = lanej >> 3, j = lanej & 7;
        int ng = f >> 3, nt = (f >> 1) & 3, ks = f & 1;
        int m16 = lane & 15, quad = lane >> 4;
        int k = ks * 32 + quad * 8 + j, n = ng * 64 + nt * 16 + m16;
        wfc2f[i2] = f2bf(Wfc2[l * 8192 + k * 128 + n]);
    } else if (i < 53248) {
        int j = i - 20480;
        int idx = j >> 12;          // l*4 + m
        int r = j & 4095;
        int l = idx >> 2, m = idx & 3;
        const float* base = (m == 0 ? Wsc0 : m == 1 ? Wl10 : m == 2 ? Wsc1 : Wl11)
                            + l * 4096;
        int u = r >> 7, rr = r & 127, a = rr >> 5, ww = rr & 31;
        Wfp[idx * 4096 + u * 128 + ww * 4 + a] = base[r];
    } else if (i < 69632) {
        int j = i - 53248;
        int l = j >> 13;
        int r = j & 8191;
        int u = r >> 7, rr = r & 127, a = rr >> 5, ww = rr & 31;
        unsigned lo = f2bf(Wl20[l * 8192 + r]);
        unsigned hi = f2bf(Wl21[l * 8192 + r]);
        Wupk[l * 8192 + u * 128 + ww * 4 + a] = lo | (hi << 16);
    }
}

// ---------------------------------------------------------------- CSR build
__global__ void csr_count(const int* __restrict__ edst, int* __restrict__ cnt, int E) {
    int e = blockIdx.x * 256 + threadIdx.x;
    if (e < E) atomicAdd(&cnt[edst[e]], 1);
}

__global__ void csr_scan(const int* __restrict__ cnt, int* __restrict__ off,
                         int* __restrict__ cursor, int N) {
    __shared__ int sums[256];
    int t = threadIdx.x;
    int chunk = (N + 255) / 256;
    int lo = t * chunk, hi = lo + chunk; if (hi > N) hi = N;
    int s = 0;
    for (int i = lo; i < hi; i++) s += cnt[i];
    sums[t] = s;
    __syncthreads();
    for (int d = 1; d < 256; d <<= 1) {
        int v = (t >= d) ? sums[t - d] : 0;
        __syncthreads();
        sums[t] += v;
        __syncthreads();
    }
    int run = (t == 0) ? 0 : sums[t - 1];
    for (int i = lo; i < hi; i++) {
        off[i] = run; cursor[i] = run;
        run += cnt[i];
    }
}

__global__ void csr_fill(const int* __restrict__ edst, const int* __restrict__ esrc,
                         const float* __restrict__ edge_vec,
                         int* __restrict__ cursor,
                         float* __restrict__ vec_csr, int* __restrict__ slot_dst, int E) {
    int e = blockIdx.x * 256 + threadIdx.x;
    if (e < E) {
        int d = edst[e];
        int p = atomicAdd(&cursor[d], 1);
        float4 vv = {edge_vec[e * 3 + 0], edge_vec[e * 3 + 1], edge_vec[e * 3 + 2],
                     __int_as_float(esrc[e])};
        *(float4*)(vec_csr + (size_t)p * 4) = vv;
        slot_dst[p] = d;
    }
}

// ---------------------------------------------------------------- node fctp
// 16 nodes/block; smem: [0,16K) w0 | [16K,32K) w1 | [32K,35K) sh
__device__ __forceinline__ void node_fctp_body(
    int blk, int path,
    const float* __restrict__ s, const float* __restrict__ v,
    const float* __restrict__ attr, const float* __restrict__ Wfp,
    float* __restrict__ sc_s, float* __restrict__ sc_v,
    float* __restrict__ xsv, int N, char* smem) {
    float* w0 = (float*)smem;
    float* w1 = (float*)(smem + 16384);
    float (*sh)[96] = (float(*)[96])(smem + 32768);
    int ln = threadIdx.x >> 5, w = threadIdx.x & 31;
    const float4* W0p = (const float4*)(Wfp + path * 8192);
    const float4* W1p = (const float4*)(Wfp + path * 8192 + 4096);
    for (int i = threadIdx.x; i < 1024; i += 256) {
        ((float4*)w0)[i] = W0p[i];
        ((float4*)w1)[i] = W1p[i];
    }
    for (int g = 0; g < 2; g++) {
        int n = blk * 16 + g * 8 + ln;
        bool valid = n < N;
        __syncthreads();
        if (valid) {
            if (path == 0) {
                sh[ln][w] = s[n * 32 + w];
            } else {
                sh[ln][w * 3 + 0] = v[n * 96 + w * 3 + 0];
                sh[ln][w * 3 + 1] = v[n * 96 + w * 3 + 1];
                sh[ln][w * 3 + 2] = v[n * 96 + w * 3 + 2];
            }
        }
        __syncthreads();
        if (!valid) continue;
        float4 at = *(const float4*)(attr + n * 4);
        if (path == 0) {
            float acc0 = 0.f, acc1 = 0.f;
            for (int u = 0; u < 32; u++) {
                float su = sh[ln][u];
                float4 W0v = *(const float4*)(w0 + u * 128 + w * 4);
                float4 W1v = *(const float4*)(w1 + u * 128 + w * 4);
                float d0 = at.x * W0v.x + at.y * W0v.y + at.z * W0v.z + at.w * W0v.w;
                float d1 = at.x * W1v.x + at.y * W1v.y + at.z * W1v.z + at.w * W1v.w;
                acc0 += su * d0;
                acc1 += su * d1;
            }
            sc_s[n * 32 + w] = acc0 * NORM128_F;
            xsv[(size_t)n * 128 + w * 4 + 3] = acc1 * NORM128_F;
        } else {
            float a00 = 0, a01 = 0, a02 = 0, a10 = 0, a11 = 0, a12 = 0;
            for (int u = 0; u < 32; u++) {
                float vu0 = sh[ln][u * 3 + 0];
                float vu1 = sh[ln][u * 3 + 1];
                float vu2 = sh[ln][u * 3 + 2];
                float4 W0v = *(const float4*)(w0 + u * 128 + w * 4);
                float4 W1v = *(const float4*)(w1 + u * 128 + w * 4);
                float d0 = at.x * W0v.x + at.y * W0v.y + at.z * W0v.z + at.w * W0v.w;
                float d1 = at.x * W1v.x + at.y * W1v.y + at.z * W1v.z + at.w * W1v.w;
                a00 += vu0 * d0; a01 += vu1 * d0; a02 += vu2 * d0;
                a10 += vu0 * d1; a11 += vu1 * d1; a12 += vu2 * d1;
            }
            sc_v[n * 96 + w * 3 + 0] = a00 * NORM128_F;
            sc_v[n * 96 + w * 3 + 1] = a01 * NORM128_F;
            sc_v[n * 96 + w * 3 + 2] = a02 * NORM128_F;
            float* xp = xsv + (size_t)n * 128 + w * 4;
            xp[0] = a10 * NORM128_F;
            xp[1] = a11 * NORM128_F;
            xp[2] = a12 * NORM128_F;
        }
    }
}

__global__ __launch_bounds__(256, 4) void node_fctp(
    int nFctpBlk,
    const float* __restrict__ s, const float* __restrict__ v,
    const float* __restrict__ attr, const float* __restrict__ Wfp,
    float* __restrict__ sc_s, float* __restrict__ sc_v,
    float* __restrict__ xsv, int N) {
    __shared__ __align__(16) char smem[35840];
    int b = blockIdx.x;
    node_fctp_body(b % nFctpBlk, b / nFctpBlk, s, v, attr, Wfp,
                   sc_s, sc_v, xsv, N, smem);
}

// ---------------------------------------------------------------- msg kernel
// Fused edge-weight MFMA + message + CSR-sorted segmented reduction.
// 128 CSR slots/block. Per-edge weights live only in LDS (no HBM round-trip).
// Phase 3: 8 quarter-waves x 16 contiguous slots; register accumulation with
// atomicAdd flushes at dst-run boundaries (slots are dst-sorted).
__global__ __launch_bounds__(256, 3) void msg_kernel(
    const float* __restrict__ vec_csr, const int* __restrict__ slot_dst,
    const unsigned short* __restrict__ wfc1f,
    const unsigned short* __restrict__ wfc2f,
    const float* __restrict__ xsv,
    float* __restrict__ agg_s, float* __restrict__ agg_v, int E) {
    __shared__ __align__(16) float sh_vec[128][4];      // y0,y1,y2,src-bits
    __shared__ float sh_len[128];
    __shared__ int   sh_dst[128];
    __shared__ __align__(16) short sh_h[128 * HS];      // 18.4 KB
    __shared__ __align__(16) unsigned sh_w[128 * 64];   // 32 KB packed bf16 pairs

    int tid = threadIdx.x;
    int e0 = blockIdx.x * 128;

    if (tid < 128) {
        int e = e0 + tid;
        float ex = 0.f, ey = 0.f, ez = 0.f, srcb = 0.f;
        int dst = -1;
        if (e < E) {
            float4 vv = *(const float4*)(vec_csr + (size_t)e * 4);
            ex = vv.x; ey = vv.y; ez = vv.z; srcb = vv.w;
            dst = slot_dst[e];
        }
        float len = sqrtf(ex * ex + ey * ey + ez * ez);
        float rinv = SQRT3_F / (len + 1e-9f);
        sh_vec[tid][0] = ex * rinv;
        sh_vec[tid][1] = ey * rinv;
        sh_vec[tid][2] = ez * rinv;
        sh_vec[tid][3] = srcb;
        sh_len[tid] = len;
        sh_dst[tid] = dst;
    }
    __syncthreads();

    int wave = tid >> 6, lane = tid & 63;
    int m16 = lane & 15, quad = lane >> 4;

    {   // ---- phase 1 (MFMA): h = silu((emb @ Wfc1)/sqrt(10)) -> bf16 sh_h
        bf16x8 bw1[4];
#pragma unroll
        for (int nt = 0; nt < 4; nt++)
            bw1[nt] = *(const bf16x8*)(wfc1f + nt * 512 + lane * 8);
#pragma unroll
        for (int mt = 0; mt < 2; mt++) {
            int e = wave * 32 + mt * 16 + m16;
            float len = sh_len[e];
            float uu = 2.0f * (len * 0.25f - 1.0f);
            float cut = (uu > 0.0f) ? 0.0f
                      : ((uu < -1.0f) ? 1.0f : 0.5f * (1.0f - __cosf(PI_F * uu)));
            bf16x8 afr;
#pragma unroll
            for (int j = 0; j < 8; j++) {
                int k = quad * 8 + j;
                float val = 0.f;
                if (k < NBASIS) {
                    float d = (len - k * CSTEP_F) * 2.5f;
                    val = __expf(-d * d) * cut;
                }
                afr[j] = (short)f2bf(val);
            }
#pragma unroll
            for (int nt = 0; nt < 4; nt++) {
                f32x4 acc = {0.f, 0.f, 0.f, 0.f};
                acc = __builtin_amdgcn_mfma_f32_16x16x32_bf16(afr, bw1[nt], acc, 0, 0, 0);
#pragma unroll
                for (int r = 0; r < 4; r++) {
                    float a = acc[r] * INV_SQRT10_F;
                    float h = a / (1.0f + __expf(-a));
                    int er = wave * 32 + mt * 16 + quad * 4 + r;
                    sh_h[er * HS + nt * 16 + m16] = (short)f2bf(h);
                }
            }
        }
    }
    __syncthreads();

    {   // ---- phase 2 (MFMA): w = (h @ Wfc2)/8 -> packed bf16 pairs in LDS
        bf16x8 afr[2][2];
#pragma unroll
        for (int mt = 0; mt < 2; mt++)
#pragma unroll
            for (int ks = 0; ks < 2; ks++) {
                int e = wave * 32 + mt * 16 + m16;
                afr[mt][ks] = *(const bf16x8*)(sh_h + e * HS + ks * 32 + quad * 8);
            }
#pragma unroll
        for (int nt = 0; nt < 4; nt++) {
            bf16x8 bfr[2][2];
#pragma unroll
            for (int ng = 0; ng < 2; ng++)
#pragma unroll
                for (int ks = 0; ks < 2; ks++)
                    bfr[ng][ks] = *(const bf16x8*)(
                        wfc2f + (((ng * 4 + nt) * 2 + ks) * 64 + lane) * 8);
#pragma unroll
            for (int mt = 0; mt < 2; mt++) {
                f32x4 a0 = {0.f, 0.f, 0.f, 0.f};
                f32x4 a1 = {0.f, 0.f, 0.f, 0.f};
                a0 = __builtin_amdgcn_mfma_f32_16x16x32_bf16(afr[mt][0], bfr[0][0], a0, 0, 0, 0);
                a0 = __builtin_amdgcn_mfma_f32_16x16x32_bf16(afr[mt][1], bfr[0][1], a0, 0, 0, 0);
                a1 = __builtin_amdgcn_mfma_f32_16x16x32_bf16(afr[mt][0], bfr[1][0], a1, 0, 0, 0);
                a1 = __builtin_amdgcn_mfma_f32_16x16x32_bf16(afr[mt][1], bfr[1][1], a1, 0, 0, 0);
                int nidx = nt * 16 + m16;
#pragma unroll
                for (int r = 0; r < 4; r++) {
                    int le = wave * 32 + mt * 16 + quad * 4 + r;
                    unsigned lo = f2bf(a0[r] * 0.125f);
                    unsigned hi = f2bf(a1[r] * 0.125f);
                    sh_w[le * 64 + nidx] = lo | (hi << 16);
                }
            }
        }
    }
    __syncthreads();

    {   // ---- phase 3: messages + dst-run segmented reduction
        int qw = tid >> 5;      // 0..7, each owns 16 contiguous slots
        int u  = tid & 31;
        float as0 = 0, as1 = 0;
        float av00 = 0, av01 = 0, av02 = 0, av10 = 0, av11 = 0, av12 = 0;
        int run = -1;

        auto flush = [&]() {
            if (run >= 0) {
                atomicAdd(&agg_s[run * 64 + u],       as0 * INV_SQRTNN_F);
                atomicAdd(&agg_s[run * 64 + 32 + u],  as1 * INV_SQRTNN_F);
                float* av = agg_v + (size_t)run * 192;
                atomicAdd(&av[u * 3 + 0],      av00 * INV_SQRTNN_F);
                atomicAdd(&av[u * 3 + 1],      av01 * INV_SQRTNN_F);
                atomicAdd(&av[u * 3 + 2],      av02 * INV_SQRTNN_F);
                atomicAdd(&av[96 + u * 3 + 0], av10 * INV_SQRTNN_F);
                atomicAdd(&av[96 + u * 3 + 1], av11 * INV_SQRTNN_F);
                atomicAdd(&av[96 + u * 3 + 2], av12 * INV_SQRTNN_F);
            }
            as0 = as1 = av00 = av01 = av02 = av10 = av11 = av12 = 0.f;
        };

        int base = qw * 16;
#pragma unroll 4
        for (int k = 0; k < 16; k++) {
            int i = base + k;
            int dst = sh_dst[i];
            if (dst < 0) continue;          // only trailing slots past E
            if (dst != run) { flush(); run = dst; }
            float y0 = sh_vec[i][0], y1 = sh_vec[i][1], y2 = sh_vec[i][2];
            int src = __float_as_int(sh_vec[i][3]);
            float4 x4 = *(const float4*)(xsv + (size_t)src * 128 + u * 4);
            unsigned q0 = sh_w[i * 64 + u];
            unsigned q1 = sh_w[i * 64 + 32 + u];
            float wa = bf2f((unsigned short)q0), wc = bf2f((unsigned short)(q0 >> 16));
            float wb = bf2f((unsigned short)q1), wd = bf2f((unsigned short)(q1 >> 16));
            as0 += wa * x4.w;
            as1 += wb * (y0 * x4.x + y1 * x4.y + y2 * x4.z) * INV_SQRT3_F;
            float t = wc * x4.w;
            av00 += t * y0;  av01 += t * y1;  av02 += t * y2;
            av10 += wd * x4.x; av11 += wd * x4.y; av12 += wd * x4.z;
        }
        flush();
    }
}

// ------------------------------------------- merged second fctp + s,v update
__global__ __launch_bounds__(256, 4) void node_update(
    const float* __restrict__ agg_s, const float* __restrict__ agg_v,
    const float* __restrict__ attr, const unsigned* __restrict__ Wupk,
    const float* __restrict__ sc_s, const float* __restrict__ sc_v,
    float* __restrict__ s, float* __restrict__ v, int N) {
    __shared__ __align__(16) unsigned pk[8192];   // 32 KB: (bf16 W20, bf16 W21)
    __shared__ float sh_as[8][64];
    __shared__ float sh_av[8][192];
    int ln = threadIdx.x >> 5, w = threadIdx.x & 31;
    for (int i = threadIdx.x; i < 2048; i += 256)
        ((uint4*)pk)[i] = ((const uint4*)Wupk)[i];
    for (int g = 0; g < 2; g++) {
        int n = blockIdx.x * 16 + g * 8 + ln;
        bool valid = n < N;
        __syncthreads();
        if (valid) {
            sh_as[ln][w] = agg_s[n * 64 + w];
            sh_as[ln][32 + w] = agg_s[n * 64 + 32 + w];
#pragma unroll
            for (int i = 0; i < 6; i++)
                sh_av[ln][w * 6 + i] = agg_v[(size_t)n * 192 + w * 6 + i];
        }
        __syncthreads();
        if (!valid) continue;
        float4 at = *(const float4*)(attr + n * 4);
        float acc_s = 0.f, a0 = 0.f, a1 = 0.f, a2 = 0.f;
        for (int u = 0; u < 64; u++) {
            float gs = sh_as[ln][u];
            float g0 = sh_av[ln][u * 3 + 0];
            float g1 = sh_av[ln][u * 3 + 1];
            float g2 = sh_av[ln][u * 3 + 2];
            uint4 pv = *(const uint4*)(pk + u * 128 + w * 4);
            float w20x = bf2f((unsigned short)pv.x), w21x = bf2f((unsigned short)(pv.x >> 16));
            float w20y = bf2f((unsigned short)pv.y), w21y = bf2f((unsigned short)(pv.y >> 16));
            float w20z = bf2f((unsigned short)pv.z), w21z = bf2f((unsigned short)(pv.z >> 16));
            float w20w = bf2f((unsigned short)pv.w), w21w = bf2f((unsigned short)(pv.w >> 16));
            float d0 = at.x * w20x + at.y * w20y + at.z * w20z + at.w * w20w;
            float d1 = at.x * w21x + at.y * w21y + at.z * w21z + at.w * w21w;
            acc_s += gs * d0;
            a0 += g0 * d1; a1 += g1 * d1; a2 += g2 * d1;
        }
        float os = acc_s * NORM256_F;
        float sn = C_S_F * sc_s[n * 32 + w] + C_X_F * os;
        float sig = 1.0f / (1.0f + __expf(-sn));
        s[n * 32 + w] += sn * sig;   // silu(sn)
        float ov0 = a0 * NORM256_F, ov1 = a1 * NORM256_F, ov2 = a2 * NORM256_F;
        v[n * 96 + w * 3 + 0] += (C_S_F * sc_v[n * 96 + w * 3 + 0] + C_X_F * ov0) * sig;
        v[n * 96 + w * 3 + 1] += (C_S_F * sc_v[n * 96 + w * 3 + 1] + C_X_F * ov1) * sig;
        v[n * 96 + w * 3 + 2] += (C_S_F * sc_v[n * 96 + w * 3 + 2] + C_X_F * ov2) * sig;
    }
}

// ---------------------------------------------------------------- readout
__global__ __launch_bounds__(256) void readout(
    const float* __restrict__ s, const float* __restrict__ attr,
    const float* __restrict__ Wread, const int* __restrict__ batch,
    float* __restrict__ out, int N, float pool_scale) {
    __shared__ float wr[2048];
    __shared__ float red[NGRAPH * 16];
    for (int i = threadIdx.x; i < 2048; i += 256) wr[i] = Wread[i];
    if (threadIdx.x < NGRAPH * 16) red[threadIdx.x] = 0.f;
    __syncthreads();
    int ln = threadIdx.x >> 4, w = threadIdx.x & 15;
    for (int g = 0; g < 4; g++) {
        int n = blockIdx.x * 64 + g * 16 + ln;
        if (n < N) {
            float4 at = *(const float4*)(attr + n * 4);
            float fa[4] = {at.x, at.y, at.z, at.w};
            float acc = 0.f;
            for (int u = 0; u < 32; u++) {
                float su = s[n * 32 + u];
                int base = u * 64 + w;
#pragma unroll
                for (int a = 0; a < 4; a++) acc += su * fa[a] * wr[base + a * 16];
            }
            atomicAdd(&red[batch[n] * 16 + w], acc);
        }
    }
    __syncthreads();
    if (threadIdx.x < NGRAPH * 16) {
        float val = red[threadIdx.x];
        if (val != 0.f)
            atomicAdd(&out[threadIdx.x], val * NORM128_F * pool_scale);
    }
}

// ---------------------------------------------------------------- launch
extern "C" void kernel_launch(void* const* d_in, const int* in_sizes, int n_in,
                              void* d_out, int out_size, void* d_ws, size_t ws_size,
                              hipStream_t stream) {
    const float* x        = (const float*)d_in[0];
    const float* nattr    = (const float*)d_in[1];
    const float* edge_vec = (const float*)d_in[2];
    const int*   batch    = (const int*)d_in[3];
    const int*   esrc     = (const int*)d_in[4];
    const int*   edst     = (const int*)d_in[5];
    const float* Wsc0  = (const float*)d_in[6];
    const float* Wsc1  = (const float*)d_in[7];
    const float* Wl10  = (const float*)d_in[8];
    const float* Wl11  = (const float*)d_in[9];
    const float* Wfc1  = (const float*)d_in[10];
    const float* Wfc2  = (const float*)d_in[11];
    const float* Wl20  = (const float*)d_in[12];
    const float* Wl21  = (const float*)d_in[13];
    const float* Wread = (const float*)d_in[14];

    int N = in_sizes[0] / (MUL * 4);
    int E = in_sizes[2] / 3;

    float* p = (float*)d_ws;
    float* vec_csr = p; p += (size_t)E * 4;     // {ex,ey,ez,src-bits}
    int* slot_dst = (int*)p; p += E;            // dst per CSR slot
    unsigned short* wfc1f = (unsigned short*)p; p += 2048;  // 4096 bf16 frags (2 layers)
    unsigned short* wfc2f = (unsigned short*)p; p += 8192;  // 16384 bf16 frags (2 layers)
    float* Wfp    = p; p += 32768;              // 2 layers x 4 matrices x 4096
    unsigned* Wupk = (unsigned*)p; p += 16384;  // 2 layers x 8192 packed pair dwords
    float* s_buf  = p; p += (size_t)N * 32;
    float* v_buf  = p; p += (size_t)N * 96;
    float* sc_s   = p; p += (size_t)N * 32;
    float* sc_v   = p; p += (size_t)N * 96;
    float* xsv    = p; p += (size_t)N * 128;    // {xv0,xv1,xv2,xs} per (n,u)
    float* agg_s  = p; p += (size_t)N * 64;     // agg_s + agg_v contiguous (one memset)
    float* agg_v  = p; p += (size_t)N * 192;
    int* cnt     = (int*)p; p += N;
    int* off     = (int*)p; p += N;
    int* cursor  = (int*)p; p += N;

    init_sv<<<(N * 128 + 255) / 256, 256, 0, stream>>>(x, s_buf, v_buf, N);
    hipMemsetAsync(d_out, 0, (size_t)out_size * sizeof(float), stream);
    setup_weights<<<272, 256, 0, stream>>>(Wfc1, Wfc2, Wsc0, Wl10, Wsc1, Wl11,
                                           Wl20, Wl21, wfc1f, wfc2f, Wfp, Wupk);

    // CSR by destination; edge data scattered into CSR order once.
    hipMemsetAsync(cnt, 0, (size_t)N * sizeof(int), stream);
    csr_count<<<(E + 255) / 256, 256, 0, stream>>>(edst, cnt, E);
    csr_scan<<<1, 256, 0, stream>>>(cnt, off, cursor, N);
    csr_fill<<<(E + 255) / 256, 256, 0, stream>>>(
        edst, esrc, edge_vec, cursor, vec_csr, slot_dst, E);

    int nE = (E + 127) / 128;
    int nF = (N + 15) / 16;

    // ---- layer 0
    hipMemsetAsync(agg_s, 0, (size_t)N * 256 * sizeof(float), stream);
    node_fctp<<<nF * 2, 256, 0, stream>>>(
        nF, s_buf, v_buf, nattr, Wfp, sc_s, sc_v, xsv, N);
    msg_kernel<<<nE, 256, 0, stream>>>(
        vec_csr, slot_dst, wfc1f, wfc2f, xsv, agg_s, agg_v, E);
    node_update<<<nF, 256, 0, stream>>>(
        agg_s, agg_v, nattr, Wupk, sc_s, sc_v, s_buf, v_buf, N);

    // ---- layer 1
    hipMemsetAsync(agg_s, 0, (size_t)N * 256 * sizeof(float), stream);
    node_fctp<<<nF * 2, 256, 0, stream>>>(
        nF, s_buf, v_buf, nattr, Wfp + 16384, sc_s, sc_v, xsv, N);
    msg_kernel<<<nE, 256, 0, stream>>>(
        vec_csr, slot_dst, wfc1f + 2048, wfc2f + 8192, xsv, agg_s, agg_v, E);
    node_update<<<nF, 256, 0, stream>>>(
        agg_s, agg_v, nattr, Wupk + 8192, sc_s, sc_v, s_buf, v_buf, N);

    float pool_scale = (float)(1.0 / sqrt((double)N / (double)NGRAPH));
    readout<<<(N + 63) / 64, 256, 0, stream>>>(
        s_buf, nattr, Wread, batch, (float*)d_out, N, pool_scale);
}

// Round 2
// 398.892 us; speedup vs baseline: 1.0941x; 1.0941x over previous
//
#include <hip/hip_runtime.h>
#include <math.h>

#define MUL 32
#define NATTR 4
#define NBASIS 10
#define HID 64
#define OUT_DIM 16
#define NGRAPH 8

#define PI_F 3.14159265358979323846f
#define SQRT3_F 1.7320508075688772f
#define INV_SQRT3_F 0.5773502691896258f
#define INV_SQRT10_F 0.31622776601683794f
#define INV_SQRTNN_F 0.17677669529663687f   // 1/sqrt(32)
#define NORM128_F 0.08838834764831845f      // 1/sqrt(128)
#define NORM256_F 0.0625f                   // 1/sqrt(256)
#define C_S_F 0.3826834323650898f           // sin(pi/8)
#define C_X_F 0.9238795325112867f           // cos(pi/8)
#define CSTEP_F (4.0f/9.0f)                 // linspace(0,4,10) step

#define HS 72    // bf16 row stride (shorts): 64 + 8 pad -> 144B, 16B-aligned

typedef __attribute__((ext_vector_type(8))) short bf16x8;
typedef __attribute__((ext_vector_type(4))) float f32x4;

__device__ inline unsigned short f2bf(float x) {
    unsigned u = __float_as_uint(x);
    u += 0x7FFF + ((u >> 16) & 1);          // round-to-nearest-even
    return (unsigned short)(u >> 16);
}
__device__ inline float bf2f(unsigned short h) {
    return __uint_as_float(((unsigned)h) << 16);
}

// ---------------------------------------------------------------- bodies
__device__ __forceinline__ void init_sv_body(
    int blk, const float* __restrict__ x,
    float* __restrict__ s, float* __restrict__ v, int N) {
    int i = blk * 256 + threadIdx.x;
    if (i >= N * 128) return;
    int n = i >> 7, c = i & 127;
    float val = x[i];
    if (c < 32) s[n * 32 + c] = val;
    else        v[n * 96 + (c - 32)] = val;
}

__device__ __forceinline__ void setup_weights_body(
    int blk,
    const float* __restrict__ Wfc1g, const float* __restrict__ Wfc2,
    const float* __restrict__ Wsc0, const float* __restrict__ Wl10,
    const float* __restrict__ Wsc1, const float* __restrict__ Wl11,
    const float* __restrict__ Wl20, const float* __restrict__ Wl21,
    unsigned short* __restrict__ wfc1f, unsigned short* __restrict__ wfc2f,
    float* __restrict__ Wfp, unsigned* __restrict__ Wupk) {
    int i = blk * 256 + threadIdx.x;
    if (i < 4096) {
        int l = i >> 11, r = i & 2047;
        int nt = r >> 9, lanej = r & 511;
        int lane = lanej >> 3, j = lanej & 7;
        int m16 = lane & 15, quad = lane >> 4;
        int k = quad * 8 + j, n = nt * 16 + m16;
        float val = (k < NBASIS) ? Wfc1g[l * 640 + k * 64 + n] : 0.f;
        wfc1f[i] = f2bf(val);
    } else if (i < 20480) {
        int i2 = i - 4096;
        int l = i2 >> 13, r = i2 & 8191;
        int f = r >> 9, lanej = r & 511;
        int lane = lanej >> 3, j = lanej & 7;
        int ng = f >> 3, nt = (f >> 1) & 3, ks = f & 1;
        int m16 = lane & 15, quad = lane >> 4;
        int k = ks * 32 + quad * 8 + j, n = ng * 64 + nt * 16 + m16;
        wfc2f[i2] = f2bf(Wfc2[l * 8192 + k * 128 + n]);
    } else if (i < 53248) {
        int j = i - 20480;
        int idx = j >> 12;          // l*4 + m
        int r = j & 4095;
        int l = idx >> 2, m = idx & 3;
        const float* base = (m == 0 ? Wsc0 : m == 1 ? Wl10 : m == 2 ? Wsc1 : Wl11)
                            + l * 4096;
        int u = r >> 7, rr = r & 127, a = rr >> 5, ww = rr & 31;
        Wfp[idx * 4096 + u * 128 + ww * 4 + a] = base[r];
    } else if (i < 69632) {
        int j = i - 53248;
        int l = j >> 13;
        int r = j & 8191;
        int u = r >> 7, rr = r & 127, a = rr >> 5, ww = rr & 31;
        unsigned lo = f2bf(Wl20[l * 8192 + r]);
        unsigned hi = f2bf(Wl21[l * 8192 + r]);
        Wupk[l * 8192 + u * 128 + ww * 4 + a] = lo | (hi << 16);
    }
}

__device__ __forceinline__ void csr_count_body(
    int blk, const int* __restrict__ edst, int* __restrict__ cnt, int E) {
    int e = blk * 256 + threadIdx.x;
    if (e < E) atomicAdd(&cnt[edst[e]], 1);
}

__device__ __forceinline__ void csr_fill_body(
    int blk, const int* __restrict__ edst, const int* __restrict__ esrc,
    const float* __restrict__ edge_vec, int* __restrict__ cursor,
    float* __restrict__ vec_csr, int* __restrict__ slot_dst, int E) {
    int e = blk * 256 + threadIdx.x;
    if (e < E) {
        int d = edst[e];
        int p = atomicAdd(&cursor[d], 1);
        float4 vv = {edge_vec[e * 3 + 0], edge_vec[e * 3 + 1], edge_vec[e * 3 + 2],
                     __int_as_float(esrc[e])};
        *(float4*)(vec_csr + (size_t)p * 4) = vv;
        slot_dst[p] = d;
    }
}

// node fctp: 16 nodes/block; smem: [0,16K) w0 | [16K,32K) w1 | [32K,35K) sh
__device__ __forceinline__ void node_fctp_body(
    int blk, int path,
    const float* __restrict__ s, const float* __restrict__ v,
    const float* __restrict__ attr, const float* __restrict__ Wfp,
    float* __restrict__ sc_s, float* __restrict__ sc_v,
    float* __restrict__ xsv, int N, char* smem) {
    float* w0 = (float*)smem;
    float* w1 = (float*)(smem + 16384);
    float (*sh)[96] = (float(*)[96])(smem + 32768);
    int ln = threadIdx.x >> 5, w = threadIdx.x & 31;
    const float4* W0p = (const float4*)(Wfp + path * 8192);
    const float4* W1p = (const float4*)(Wfp + path * 8192 + 4096);
    for (int i = threadIdx.x; i < 1024; i += 256) {
        ((float4*)w0)[i] = W0p[i];
        ((float4*)w1)[i] = W1p[i];
    }
    for (int g = 0; g < 2; g++) {
        int n = blk * 16 + g * 8 + ln;
        bool valid = n < N;
        __syncthreads();
        if (valid) {
            if (path == 0) {
                sh[ln][w] = s[n * 32 + w];
            } else {
                sh[ln][w * 3 + 0] = v[n * 96 + w * 3 + 0];
                sh[ln][w * 3 + 1] = v[n * 96 + w * 3 + 1];
                sh[ln][w * 3 + 2] = v[n * 96 + w * 3 + 2];
            }
        }
        __syncthreads();
        if (!valid) continue;
        float4 at = *(const float4*)(attr + n * 4);
        if (path == 0) {
            float acc0 = 0.f, acc1 = 0.f;
            for (int u = 0; u < 32; u++) {
                float su = sh[ln][u];
                float4 W0v = *(const float4*)(w0 + u * 128 + w * 4);
                float4 W1v = *(const float4*)(w1 + u * 128 + w * 4);
                float d0 = at.x * W0v.x + at.y * W0v.y + at.z * W0v.z + at.w * W0v.w;
                float d1 = at.x * W1v.x + at.y * W1v.y + at.z * W1v.z + at.w * W1v.w;
                acc0 += su * d0;
                acc1 += su * d1;
            }
            sc_s[n * 32 + w] = acc0 * NORM128_F;
            xsv[(size_t)n * 128 + w * 4 + 3] = acc1 * NORM128_F;
        } else {
            float a00 = 0, a01 = 0, a02 = 0, a10 = 0, a11 = 0, a12 = 0;
            for (int u = 0; u < 32; u++) {
                float vu0 = sh[ln][u * 3 + 0];
                float vu1 = sh[ln][u * 3 + 1];
                float vu2 = sh[ln][u * 3 + 2];
                float4 W0v = *(const float4*)(w0 + u * 128 + w * 4);
                float4 W1v = *(const float4*)(w1 + u * 128 + w * 4);
                float d0 = at.x * W0v.x + at.y * W0v.y + at.z * W0v.z + at.w * W0v.w;
                float d1 = at.x * W1v.x + at.y * W1v.y + at.z * W1v.z + at.w * W1v.w;
                a00 += vu0 * d0; a01 += vu1 * d0; a02 += vu2 * d0;
                a10 += vu0 * d1; a11 += vu1 * d1; a12 += vu2 * d1;
            }
            sc_v[n * 96 + w * 3 + 0] = a00 * NORM128_F;
            sc_v[n * 96 + w * 3 + 1] = a01 * NORM128_F;
            sc_v[n * 96 + w * 3 + 2] = a02 * NORM128_F;
            float* xp = xsv + (size_t)n * 128 + w * 4;
            xp[0] = a10 * NORM128_F;
            xp[1] = a11 * NORM128_F;
            xp[2] = a12 * NORM128_F;
        }
    }
}

// node update: smem [0,32K) pk | [32K,34K) sh_as | [34K,40K) sh_av
__device__ __forceinline__ void node_update_body(
    int blk, const float* __restrict__ agg_s, const float* __restrict__ agg_v,
    const float* __restrict__ attr, const unsigned* __restrict__ Wupk,
    const float* __restrict__ sc_s, const float* __restrict__ sc_v,
    float* __restrict__ s, float* __restrict__ v, int N, char* smem) {
    unsigned* pk = (unsigned*)smem;
    float (*sh_as)[64]  = (float(*)[64])(smem + 32768);
    float (*sh_av)[192] = (float(*)[192])(smem + 32768 + 2048);
    int ln = threadIdx.x >> 5, w = threadIdx.x & 31;
    for (int i = threadIdx.x; i < 2048; i += 256)
        ((uint4*)pk)[i] = ((const uint4*)Wupk)[i];
    for (int g = 0; g < 2; g++) {
        int n = blk * 16 + g * 8 + ln;
        bool valid = n < N;
        __syncthreads();
        if (valid) {
            sh_as[ln][w] = agg_s[n * 64 + w];
            sh_as[ln][32 + w] = agg_s[n * 64 + 32 + w];
#pragma unroll
            for (int i = 0; i < 6; i++)
                sh_av[ln][w * 6 + i] = agg_v[(size_t)n * 192 + w * 6 + i];
        }
        __syncthreads();
        if (!valid) continue;
        float4 at = *(const float4*)(attr + n * 4);
        float acc_s = 0.f, a0 = 0.f, a1 = 0.f, a2 = 0.f;
        for (int u = 0; u < 64; u++) {
            float gs = sh_as[ln][u];
            float g0 = sh_av[ln][u * 3 + 0];
            float g1 = sh_av[ln][u * 3 + 1];
            float g2 = sh_av[ln][u * 3 + 2];
            uint4 pv = *(const uint4*)(pk + u * 128 + w * 4);
            float w20x = bf2f((unsigned short)pv.x), w21x = bf2f((unsigned short)(pv.x >> 16));
            float w20y = bf2f((unsigned short)pv.y), w21y = bf2f((unsigned short)(pv.y >> 16));
            float w20z = bf2f((unsigned short)pv.z), w21z = bf2f((unsigned short)(pv.z >> 16));
            float w20w = bf2f((unsigned short)pv.w), w21w = bf2f((unsigned short)(pv.w >> 16));
            float d0 = at.x * w20x + at.y * w20y + at.z * w20z + at.w * w20w;
            float d1 = at.x * w21x + at.y * w21y + at.z * w21z + at.w * w21w;
            acc_s += gs * d0;
            a0 += g0 * d1; a1 += g1 * d1; a2 += g2 * d1;
        }
        float os = acc_s * NORM256_F;
        float sn = C_S_F * sc_s[n * 32 + w] + C_X_F * os;
        float sig = 1.0f / (1.0f + __expf(-sn));
        s[n * 32 + w] += sn * sig;   // silu(sn)
        float ov0 = a0 * NORM256_F, ov1 = a1 * NORM256_F, ov2 = a2 * NORM256_F;
        v[n * 96 + w * 3 + 0] += (C_S_F * sc_v[n * 96 + w * 3 + 0] + C_X_F * ov0) * sig;
        v[n * 96 + w * 3 + 1] += (C_S_F * sc_v[n * 96 + w * 3 + 1] + C_X_F * ov1) * sig;
        v[n * 96 + w * 3 + 2] += (C_S_F * sc_v[n * 96 + w * 3 + 2] + C_X_F * ov2) * sig;
    }
}

// ---------------------------------------------------------------- mega kernels
__global__ __launch_bounds__(256) void mega1(
    int nInit, int nSetup,
    const float* __restrict__ x, float* __restrict__ s, float* __restrict__ v,
    const float* __restrict__ Wfc1g, const float* __restrict__ Wfc2,
    const float* __restrict__ Wsc0, const float* __restrict__ Wl10,
    const float* __restrict__ Wsc1, const float* __restrict__ Wl11,
    const float* __restrict__ Wl20, const float* __restrict__ Wl21,
    unsigned short* __restrict__ wfc1f, unsigned short* __restrict__ wfc2f,
    float* __restrict__ Wfp, unsigned* __restrict__ Wupk,
    const int* __restrict__ edst, int* __restrict__ cnt, int N, int E) {
    int b = blockIdx.x;
    if (b < nInit) { init_sv_body(b, x, s, v, N); return; }
    b -= nInit;
    if (b < nSetup) {
        setup_weights_body(b, Wfc1g, Wfc2, Wsc0, Wl10, Wsc1, Wl11, Wl20, Wl21,
                           wfc1f, wfc2f, Wfp, Wupk);
        return;
    }
    b -= nSetup;
    csr_count_body(b, edst, cnt, E);
}

__global__ void csr_scan(const int* __restrict__ cnt, int* __restrict__ off,
                         int* __restrict__ cursor, int N) {
    __shared__ int sums[256];
    int t = threadIdx.x;
    int chunk = (N + 255) / 256;
    int lo = t * chunk, hi = lo + chunk; if (hi > N) hi = N;
    int s = 0;
    for (int i = lo; i < hi; i++) s += cnt[i];
    sums[t] = s;
    __syncthreads();
    for (int d = 1; d < 256; d <<= 1) {
        int v = (t >= d) ? sums[t - d] : 0;
        __syncthreads();
        sums[t] += v;
        __syncthreads();
    }
    int run = (t == 0) ? 0 : sums[t - 1];
    for (int i = lo; i < hi; i++) {
        off[i] = run; cursor[i] = run;
        run += cnt[i];
    }
}

// csr_fill || fctp(layer0, both paths) || zero agg ping-pong buffers
__global__ __launch_bounds__(256, 4) void mega2(
    int nFill, int nF,
    const int* __restrict__ edst, const int* __restrict__ esrc,
    const float* __restrict__ edge_vec, int* __restrict__ cursor,
    float* __restrict__ vec_csr, int* __restrict__ slot_dst, int E,
    const float* __restrict__ s, const float* __restrict__ v,
    const float* __restrict__ attr, const float* __restrict__ Wfp,
    float* __restrict__ sc_s, float* __restrict__ sc_v,
    float* __restrict__ xsv, int N,
    float* __restrict__ zero_base, int nZeroF4) {
    __shared__ __align__(16) char smem[35840];
    int b = blockIdx.x;
    if (b < nFill) {
        csr_fill_body(b, edst, esrc, edge_vec, cursor, vec_csr, slot_dst, E);
        return;
    }
    b -= nFill;
    if (b < 2 * nF) {
        node_fctp_body(b % nF, b / nF, s, v, attr, Wfp, sc_s, sc_v, xsv, N, smem);
        return;
    }
    b -= 2 * nF;
    int i = b * 256 + threadIdx.x;
    if (i < nZeroF4) {
        float4 z = {0.f, 0.f, 0.f, 0.f};
        ((float4*)zero_base)[i] = z;
    }
}

// ---------------------------------------------------------------- msg kernel
// Fused edge-weight MFMA + message + CSR-sorted segmented reduction.
// 128 CSR slots/block. LDS 35.8KB -> 4 blocks/CU. sh_h aliases sh_w (phase-2
// A-fragments are fully register-resident before any sh_w write).
// Phase 3: batch-4 software pipeline (4 independent xsv loads in flight).
__global__ __launch_bounds__(256, 4) void msg_kernel(
    const float* __restrict__ vec_csr, const int* __restrict__ slot_dst,
    const unsigned short* __restrict__ wfc1f,
    const unsigned short* __restrict__ wfc2f,
    const float* __restrict__ xsv,
    float* __restrict__ agg_s, float* __restrict__ agg_v, int E) {
    __shared__ __align__(16) float sh_vec[128][4];      // y0,y1,y2,src-bits
    __shared__ float sh_len[128];
    __shared__ int   sh_dst[128];
    __shared__ __align__(16) unsigned sh_w[128 * 64];   // 32 KB packed bf16 pairs
    short* sh_h = (short*)sh_w;                          // aliased: 128*HS = 18.4 KB

    int tid = threadIdx.x;
    int e0 = blockIdx.x * 128;

    if (tid < 128) {
        int e = e0 + tid;
        float ex = 0.f, ey = 0.f, ez = 0.f, srcb = 0.f;
        int dst = -1;
        if (e < E) {
            float4 vv = *(const float4*)(vec_csr + (size_t)e * 4);
            ex = vv.x; ey = vv.y; ez = vv.z; srcb = vv.w;
            dst = slot_dst[e];
        }
        float len = sqrtf(ex * ex + ey * ey + ez * ez);
        float rinv = SQRT3_F / (len + 1e-9f);
        sh_vec[tid][0] = ex * rinv;
        sh_vec[tid][1] = ey * rinv;
        sh_vec[tid][2] = ez * rinv;
        sh_vec[tid][3] = srcb;
        sh_len[tid] = len;
        sh_dst[tid] = dst;
    }
    __syncthreads();

    int wave = tid >> 6, lane = tid & 63;
    int m16 = lane & 15, quad = lane >> 4;

    {   // ---- phase 1 (MFMA): h = silu((emb @ Wfc1)/sqrt(10)) -> bf16 sh_h
        bf16x8 bw1[4];
#pragma unroll
        for (int nt = 0; nt < 4; nt++)
            bw1[nt] = *(const bf16x8*)(wfc1f + nt * 512 + lane * 8);
#pragma unroll
        for (int mt = 0; mt < 2; mt++) {
            int e = wave * 32 + mt * 16 + m16;
            float len = sh_len[e];
            float uu = 2.0f * (len * 0.25f - 1.0f);
            float cut = (uu > 0.0f) ? 0.0f
                      : ((uu < -1.0f) ? 1.0f : 0.5f * (1.0f - __cosf(PI_F * uu)));
            bf16x8 afr;
#pragma unroll
            for (int j = 0; j < 8; j++) {
                int k = quad * 8 + j;
                float val = 0.f;
                if (k < NBASIS) {
                    float d = (len - k * CSTEP_F) * 2.5f;
                    val = __expf(-d * d) * cut;
                }
                afr[j] = (short)f2bf(val);
            }
#pragma unroll
            for (int nt = 0; nt < 4; nt++) {
                f32x4 acc = {0.f, 0.f, 0.f, 0.f};
                acc = __builtin_amdgcn_mfma_f32_16x16x32_bf16(afr, bw1[nt], acc, 0, 0, 0);
#pragma unroll
                for (int r = 0; r < 4; r++) {
                    float a = acc[r] * INV_SQRT10_F;
                    float h = a / (1.0f + __expf(-a));
                    int er = wave * 32 + mt * 16 + quad * 4 + r;
                    sh_h[er * HS + nt * 16 + m16] = (short)f2bf(h);
                }
            }
        }
    }
    __syncthreads();

    {   // ---- phase 2 (MFMA): w = (h @ Wfc2)/8 -> packed bf16 pairs in sh_w
        bf16x8 afr[2][2];
#pragma unroll
        for (int mt = 0; mt < 2; mt++)
#pragma unroll
            for (int ks = 0; ks < 2; ks++) {
                int e = wave * 32 + mt * 16 + m16;
                afr[mt][ks] = *(const bf16x8*)(sh_h + e * HS + ks * 32 + quad * 8);
            }
        __syncthreads();   // all sh_h reads done -> safe to overwrite via sh_w
#pragma unroll
        for (int nt = 0; nt < 4; nt++) {
            bf16x8 bfr[2][2];
#pragma unroll
            for (int ng = 0; ng < 2; ng++)
#pragma unroll
                for (int ks = 0; ks < 2; ks++)
                    bfr[ng][ks] = *(const bf16x8*)(
                        wfc2f + (((ng * 4 + nt) * 2 + ks) * 64 + lane) * 8);
#pragma unroll
            for (int mt = 0; mt < 2; mt++) {
                f32x4 a0 = {0.f, 0.f, 0.f, 0.f};
                f32x4 a1 = {0.f, 0.f, 0.f, 0.f};
                a0 = __builtin_amdgcn_mfma_f32_16x16x32_bf16(afr[mt][0], bfr[0][0], a0, 0, 0, 0);
                a0 = __builtin_amdgcn_mfma_f32_16x16x32_bf16(afr[mt][1], bfr[0][1], a0, 0, 0, 0);
                a1 = __builtin_amdgcn_mfma_f32_16x16x32_bf16(afr[mt][0], bfr[1][0], a1, 0, 0, 0);
                a1 = __builtin_amdgcn_mfma_f32_16x16x32_bf16(afr[mt][1], bfr[1][1], a1, 0, 0, 0);
                int nidx = nt * 16 + m16;
#pragma unroll
                for (int r = 0; r < 4; r++) {
                    int le = wave * 32 + mt * 16 + quad * 4 + r;
                    unsigned lo = f2bf(a0[r] * 0.125f);
                    unsigned hi = f2bf(a1[r] * 0.125f);
                    sh_w[le * 64 + nidx] = lo | (hi << 16);
                }
            }
        }
    }
    __syncthreads();

    {   // ---- phase 3: messages + dst-run segmented reduction (batch-4 pipeline)
        int qw = tid >> 5;      // 0..7, each owns 16 contiguous slots
        int u  = tid & 31;
        float as0 = 0, as1 = 0;
        float av00 = 0, av01 = 0, av02 = 0, av10 = 0, av11 = 0, av12 = 0;
        int run = -1;

        auto flush = [&]() {
            if (run >= 0) {
                atomicAdd(&agg_s[run * 64 + u],       as0 * INV_SQRTNN_F);
                atomicAdd(&agg_s[run * 64 + 32 + u],  as1 * INV_SQRTNN_F);
                float* av = agg_v + (size_t)run * 192;
                atomicAdd(&av[u * 3 + 0],      av00 * INV_SQRTNN_F);
                atomicAdd(&av[u * 3 + 1],      av01 * INV_SQRTNN_F);
                atomicAdd(&av[u * 3 + 2],      av02 * INV_SQRTNN_F);
                atomicAdd(&av[96 + u * 3 + 0], av10 * INV_SQRTNN_F);
                atomicAdd(&av[96 + u * 3 + 1], av11 * INV_SQRTNN_F);
                atomicAdd(&av[96 + u * 3 + 2], av12 * INV_SQRTNN_F);
            }
            as0 = as1 = av00 = av01 = av02 = av10 = av11 = av12 = 0.f;
        };

        int base = qw * 16;
#pragma unroll
        for (int kk = 0; kk < 16; kk += 4) {
            float4 x4v[4];
            unsigned q0v[4], q1v[4];
            int dstv[4];
            float y0v[4], y1v[4], y2v[4];
#pragma unroll
            for (int t = 0; t < 4; t++) {
                int i = base + kk + t;
                dstv[t] = sh_dst[i];
                float4 sv = *(const float4*)&sh_vec[i][0];
                y0v[t] = sv.x; y1v[t] = sv.y; y2v[t] = sv.z;
                int src = __float_as_int(sv.w);
                x4v[t] = *(const float4*)(xsv + (size_t)src * 128 + u * 4);
                q0v[t] = sh_w[i * 64 + u];
                q1v[t] = sh_w[i * 64 + 32 + u];
            }
#pragma unroll
            for (int t = 0; t < 4; t++) {
                int dst = dstv[t];
                if (dst != run) { flush(); run = dst; }
                float wa = bf2f((unsigned short)q0v[t]), wc = bf2f((unsigned short)(q0v[t] >> 16));
                float wb = bf2f((unsigned short)q1v[t]), wd = bf2f((unsigned short)(q1v[t] >> 16));
                float4 x4 = x4v[t];
                as0 += wa * x4.w;
                as1 += wb * (y0v[t] * x4.x + y1v[t] * x4.y + y2v[t] * x4.z) * INV_SQRT3_F;
                float tt = wc * x4.w;
                av00 += tt * y0v[t];  av01 += tt * y1v[t];  av02 += tt * y2v[t];
                av10 += wd * x4.x; av11 += wd * x4.y; av12 += wd * x4.z;
            }
        }
        flush();
    }
}

// ------------------------------- node update (layer l) + fctp (layer l+1)
__global__ __launch_bounds__(256, 4) void update_fctp(
    const float* __restrict__ agg_s, const float* __restrict__ agg_v,
    const float* __restrict__ attr, const unsigned* __restrict__ Wupk,
    float* __restrict__ sc_s, float* __restrict__ sc_v,
    float* __restrict__ s, float* __restrict__ v,
    const float* __restrict__ Wfp_next, float* __restrict__ xsv,
    int N, int do_fctp) {
    __shared__ __align__(16) char smem[40960];
    node_update_body(blockIdx.x, agg_s, agg_v, attr, Wupk, sc_s, sc_v, s, v, N, smem);
    if (do_fctp) {
        __syncthreads();   // pk/sh_as reads done; s,v global writes drained
        node_fctp_body(blockIdx.x, 0, s, v, attr, Wfp_next, sc_s, sc_v, xsv, N, smem);
        __syncthreads();   // w0/w1 reads done before path-1 reload
        node_fctp_body(blockIdx.x, 1, s, v, attr, Wfp_next, sc_s, sc_v, xsv, N, smem);
    }
}

// ---------------------------------------------------------------- readout
__global__ __launch_bounds__(256) void readout(
    const float* __restrict__ s, const float* __restrict__ attr,
    const float* __restrict__ Wread, const int* __restrict__ batch,
    float* __restrict__ out, int N, float pool_scale) {
    __shared__ float wr[2048];
    __shared__ float red[NGRAPH * 16];
    for (int i = threadIdx.x; i < 2048; i += 256) wr[i] = Wread[i];
    if (threadIdx.x < NGRAPH * 16) red[threadIdx.x] = 0.f;
    __syncthreads();
    int ln = threadIdx.x >> 4, w = threadIdx.x & 15;
    for (int g = 0; g < 4; g++) {
        int n = blockIdx.x * 64 + g * 16 + ln;
        if (n < N) {
            float4 at = *(const float4*)(attr + n * 4);
            float fa[4] = {at.x, at.y, at.z, at.w};
            float acc = 0.f;
            for (int u = 0; u < 32; u++) {
                float su = s[n * 32 + u];
                int base = u * 64 + w;
#pragma unroll
                for (int a = 0; a < 4; a++) acc += su * fa[a] * wr[base + a * 16];
            }
            atomicAdd(&red[batch[n] * 16 + w], acc);
        }
    }
    __syncthreads();
    if (threadIdx.x < NGRAPH * 16) {
        float val = red[threadIdx.x];
        if (val != 0.f)
            atomicAdd(&out[threadIdx.x], val * NORM128_F * pool_scale);
    }
}

// ---------------------------------------------------------------- launch
extern "C" void kernel_launch(void* const* d_in, const int* in_sizes, int n_in,
                              void* d_out, int out_size, void* d_ws, size_t ws_size,
                              hipStream_t stream) {
    const float* x        = (const float*)d_in[0];
    const float* nattr    = (const float*)d_in[1];
    const float* edge_vec = (const float*)d_in[2];
    const int*   batch    = (const int*)d_in[3];
    const int*   esrc     = (const int*)d_in[4];
    const int*   edst     = (const int*)d_in[5];
    const float* Wsc0  = (const float*)d_in[6];
    const float* Wsc1  = (const float*)d_in[7];
    const float* Wl10  = (const float*)d_in[8];
    const float* Wl11  = (const float*)d_in[9];
    const float* Wfc1  = (const float*)d_in[10];
    const float* Wfc2  = (const float*)d_in[11];
    const float* Wl20  = (const float*)d_in[12];
    const float* Wl21  = (const float*)d_in[13];
    const float* Wread = (const float*)d_in[14];

    int N = in_sizes[0] / (MUL * 4);
    int E = in_sizes[2] / 3;

    float* p = (float*)d_ws;
    float* vec_csr = p; p += (size_t)E * 4;     // {ex,ey,ez,src-bits}
    int* slot_dst = (int*)p; p += E;            // dst per CSR slot
    unsigned short* wfc1f = (unsigned short*)p; p += 2048;  // 4096 bf16 frags (2 layers)
    unsigned short* wfc2f = (unsigned short*)p; p += 8192;  // 16384 bf16 frags (2 layers)
    float* Wfp    = p; p += 32768;              // 2 layers x 4 matrices x 4096
    unsigned* Wupk = (unsigned*)p; p += 16384;  // 2 layers x 8192 packed pair dwords
    float* s_buf  = p; p += (size_t)N * 32;
    float* v_buf  = p; p += (size_t)N * 96;
    float* sc_s   = p; p += (size_t)N * 32;
    float* sc_v   = p; p += (size_t)N * 96;
    float* xsv    = p; p += (size_t)N * 128;    // {xv0,xv1,xv2,xs} per (n,u)
    float* aggA_s = p; p += (size_t)N * 64;     // ping-pong agg buffers, contiguous
    float* aggA_v = p; p += (size_t)N * 192;
    float* aggB_s = p; p += (size_t)N * 64;
    float* aggB_v = p; p += (size_t)N * 192;
    int* cnt     = (int*)p; p += N;
    int* off     = (int*)p; p += N;
    int* cursor  = (int*)p; p += N;

    hipMemsetAsync(d_out, 0, (size_t)out_size * sizeof(float), stream);
    hipMemsetAsync(cnt, 0, (size_t)N * sizeof(int), stream);

    int nInit  = (N * 128 + 255) / 256;
    int nSetup = 272;
    int nCount = (E + 255) / 256;
    mega1<<<nInit + nSetup + nCount, 256, 0, stream>>>(
        nInit, nSetup, x, s_buf, v_buf,
        Wfc1, Wfc2, Wsc0, Wl10, Wsc1, Wl11, Wl20, Wl21,
        wfc1f, wfc2f, Wfp, Wupk, edst, cnt, N, E);

    csr_scan<<<1, 256, 0, stream>>>(cnt, off, cursor, N);

    int nFill = (E + 255) / 256;
    int nF = (N + 15) / 16;
    int nZeroF4 = N * 128;                      // 2 x N*256 floats as float4
    int nZeroBlk = (nZeroF4 + 255) / 256;
    mega2<<<nFill + 2 * nF + nZeroBlk, 256, 0, stream>>>(
        nFill, nF, edst, esrc, edge_vec, cursor, vec_csr, slot_dst, E,
        s_buf, v_buf, nattr, Wfp, sc_s, sc_v, xsv, N, aggA_s, nZeroF4);

    int nE = (E + 127) / 128;

    // ---- layer 0
    msg_kernel<<<nE, 256, 0, stream>>>(
        vec_csr, slot_dst, wfc1f, wfc2f, xsv, aggA_s, aggA_v, E);
    update_fctp<<<nF, 256, 0, stream>>>(
        aggA_s, aggA_v, nattr, Wupk, sc_s, sc_v, s_buf, v_buf,
        Wfp + 16384, xsv, N, 1);

    // ---- layer 1
    msg_kernel<<<nE, 256, 0, stream>>>(
        vec_csr, slot_dst, wfc1f + 2048, wfc2f + 8192, xsv, aggB_s, aggB_v, E);
    update_fctp<<<nF, 256, 0, stream>>>(
        aggB_s, aggB_v, nattr, Wupk + 8192, sc_s, sc_v, s_buf, v_buf,
        (const float*)0, xsv, N, 0);

    float pool_scale = (float)(1.0 / sqrt((double)N / (double)NGRAPH));
    readout<<<(N + 63) / 64, 256, 0, stream>>>(
        s_buf, nattr, Wread, batch, (float*)d_out, N, pool_scale);
}

// Round 3
// 370.212 us; speedup vs baseline: 1.1789x; 1.0775x over previous
//
#include <hip/hip_runtime.h>
#include <math.h>

#define MUL 32
#define NATTR 4
#define NBASIS 10
#define HID 64
#define OUT_DIM 16
#define NGRAPH 8

#define PI_F 3.14159265358979323846f
#define SQRT3_F 1.7320508075688772f
#define INV_SQRT3_F 0.5773502691896258f
#define INV_SQRT10_F 0.31622776601683794f
#define INV_SQRTNN_F 0.17677669529663687f   // 1/sqrt(32)
#define NORM128_F 0.08838834764831845f      // 1/sqrt(128)
#define NORM256_F 0.0625f                   // 1/sqrt(256)
#define C_S_F 0.3826834323650898f           // sin(pi/8)
#define C_X_F 0.9238795325112867f           // cos(pi/8)
#define CSTEP_F (4.0f/9.0f)                 // linspace(0,4,10) step

#define HS 72     // bf16 row stride (shorts): 64 + 8 pad -> 144B, 16B-aligned
#define ACC_CAP 16  // LDS accumulator: max node range per 128-slot block (fast path)

typedef __attribute__((ext_vector_type(8))) short bf16x8;
typedef __attribute__((ext_vector_type(4))) float f32x4;

__device__ inline unsigned short f2bf(float x) {
    unsigned u = __float_as_uint(x);
    u += 0x7FFF + ((u >> 16) & 1);          // round-to-nearest-even
    return (unsigned short)(u >> 16);
}
__device__ inline float bf2f(unsigned short h) {
    return __uint_as_float(((unsigned)h) << 16);
}

// ---------------------------------------------------------------- bodies
__device__ __forceinline__ void init_sv_body(
    int blk, const float* __restrict__ x,
    float* __restrict__ s, float* __restrict__ v, int N) {
    int i = blk * 256 + threadIdx.x;
    if (i >= N * 128) return;
    int n = i >> 7, c = i & 127;
    float val = x[i];
    if (c < 32) s[n * 32 + c] = val;
    else        v[n * 96 + (c - 32)] = val;
}

__device__ __forceinline__ void setup_weights_body(
    int blk,
    const float* __restrict__ Wfc1g, const float* __restrict__ Wfc2,
    const float* __restrict__ Wsc0, const float* __restrict__ Wl10,
    const float* __restrict__ Wsc1, const float* __restrict__ Wl11,
    const float* __restrict__ Wl20, const float* __restrict__ Wl21,
    unsigned short* __restrict__ wfc1f, unsigned short* __restrict__ wfc2f,
    float* __restrict__ Wfp, unsigned* __restrict__ Wupk) {
    int i = blk * 256 + threadIdx.x;
    if (i < 4096) {
        int l = i >> 11, r = i & 2047;
        int nt = r >> 9, lanej = r & 511;
        int lane = lanej >> 3, j = lanej & 7;
        int m16 = lane & 15, quad = lane >> 4;
        int k = quad * 8 + j, n = nt * 16 + m16;
        float val = (k < NBASIS) ? Wfc1g[l * 640 + k * 64 + n] : 0.f;
        wfc1f[i] = f2bf(val);
    } else if (i < 20480) {
        int i2 = i - 4096;
        int l = i2 >> 13, r = i2 & 8191;
        int f = r >> 9, lanej = r & 511;
        int lane = lanej >> 3, j = lanej & 7;
        int ng = f >> 3, nt = (f >> 1) & 3, ks = f & 1;
        int m16 = lane & 15, quad = lane >> 4;
        int k = ks * 32 + quad * 8 + j, n = ng * 64 + nt * 16 + m16;
        wfc2f[i2] = f2bf(Wfc2[l * 8192 + k * 128 + n]);
    } else if (i < 53248) {
        int j = i - 20480;
        int idx = j >> 12;          // l*4 + m
        int r = j & 4095;
        int l = idx >> 2, m = idx & 3;
        const float* base = (m == 0 ? Wsc0 : m == 1 ? Wl10 : m == 2 ? Wsc1 : Wl11)
                            + l * 4096;
        int u = r >> 7, rr = r & 127, a = rr >> 5, ww = rr & 31;
        Wfp[idx * 4096 + u * 128 + ww * 4 + a] = base[r];
    } else if (i < 69632) {
        int j = i - 53248;
        int l = j >> 13;
        int r = j & 8191;
        int u = r >> 7, rr = r & 127, a = rr >> 5, ww = rr & 31;
        unsigned lo = f2bf(Wl20[l * 8192 + r]);
        unsigned hi = f2bf(Wl21[l * 8192 + r]);
        Wupk[l * 8192 + u * 128 + ww * 4 + a] = lo | (hi << 16);
    }
}

__device__ __forceinline__ void csr_count_body(
    int blk, const int* __restrict__ edst, int* __restrict__ cnt, int E) {
    int e = blk * 256 + threadIdx.x;
    if (e < E) atomicAdd(&cnt[edst[e]], 1);
}

__device__ __forceinline__ void csr_fill_body(
    int blk, const int* __restrict__ edst, const int* __restrict__ esrc,
    const float* __restrict__ edge_vec, int* __restrict__ cursor,
    float* __restrict__ vec_csr, int* __restrict__ slot_dst, int E) {
    int e = blk * 256 + threadIdx.x;
    if (e < E) {
        int d = edst[e];
        int p = atomicAdd(&cursor[d], 1);
        float4 vv = {edge_vec[e * 3 + 0], edge_vec[e * 3 + 1], edge_vec[e * 3 + 2],
                     __int_as_float(esrc[e])};
        *(float4*)(vec_csr + (size_t)p * 4) = vv;
        slot_dst[p] = d;
    }
}

// node fctp: 16 nodes/block; smem: [0,16K) w0 | [16K,32K) w1 | [32K,35K) sh
__device__ __forceinline__ void node_fctp_body(
    int blk, int path,
    const float* __restrict__ s, const float* __restrict__ v,
    const float* __restrict__ attr, const float* __restrict__ Wfp,
    float* __restrict__ sc_s, float* __restrict__ sc_v,
    float* __restrict__ xsv, int N, char* smem) {
    float* w0 = (float*)smem;
    float* w1 = (float*)(smem + 16384);
    float (*sh)[96] = (float(*)[96])(smem + 32768);
    int ln = threadIdx.x >> 5, w = threadIdx.x & 31;
    const float4* W0p = (const float4*)(Wfp + path * 8192);
    const float4* W1p = (const float4*)(Wfp + path * 8192 + 4096);
    for (int i = threadIdx.x; i < 1024; i += 256) {
        ((float4*)w0)[i] = W0p[i];
        ((float4*)w1)[i] = W1p[i];
    }
    for (int g = 0; g < 2; g++) {
        int n = blk * 16 + g * 8 + ln;
        bool valid = n < N;
        __syncthreads();
        if (valid) {
            if (path == 0) {
                sh[ln][w] = s[n * 32 + w];
            } else {
                sh[ln][w * 3 + 0] = v[n * 96 + w * 3 + 0];
                sh[ln][w * 3 + 1] = v[n * 96 + w * 3 + 1];
                sh[ln][w * 3 + 2] = v[n * 96 + w * 3 + 2];
            }
        }
        __syncthreads();
        if (!valid) continue;
        float4 at = *(const float4*)(attr + n * 4);
        if (path == 0) {
            float acc0 = 0.f, acc1 = 0.f;
            for (int u = 0; u < 32; u++) {
                float su = sh[ln][u];
                float4 W0v = *(const float4*)(w0 + u * 128 + w * 4);
                float4 W1v = *(const float4*)(w1 + u * 128 + w * 4);
                float d0 = at.x * W0v.x + at.y * W0v.y + at.z * W0v.z + at.w * W0v.w;
                float d1 = at.x * W1v.x + at.y * W1v.y + at.z * W1v.z + at.w * W1v.w;
                acc0 += su * d0;
                acc1 += su * d1;
            }
            sc_s[n * 32 + w] = acc0 * NORM128_F;
            xsv[(size_t)n * 128 + w * 4 + 3] = acc1 * NORM128_F;
        } else {
            float a00 = 0, a01 = 0, a02 = 0, a10 = 0, a11 = 0, a12 = 0;
            for (int u = 0; u < 32; u++) {
                float vu0 = sh[ln][u * 3 + 0];
                float vu1 = sh[ln][u * 3 + 1];
                float vu2 = sh[ln][u * 3 + 2];
                float4 W0v = *(const float4*)(w0 + u * 128 + w * 4);
                float4 W1v = *(const float4*)(w1 + u * 128 + w * 4);
                float d0 = at.x * W0v.x + at.y * W0v.y + at.z * W0v.z + at.w * W0v.w;
                float d1 = at.x * W1v.x + at.y * W1v.y + at.z * W1v.z + at.w * W1v.w;
                a00 += vu0 * d0; a01 += vu1 * d0; a02 += vu2 * d0;
                a10 += vu0 * d1; a11 += vu1 * d1; a12 += vu2 * d1;
            }
            sc_v[n * 96 + w * 3 + 0] = a00 * NORM128_F;
            sc_v[n * 96 + w * 3 + 1] = a01 * NORM128_F;
            sc_v[n * 96 + w * 3 + 2] = a02 * NORM128_F;
            float* xp = xsv + (size_t)n * 128 + w * 4;
            xp[0] = a10 * NORM128_F;
            xp[1] = a11 * NORM128_F;
            xp[2] = a12 * NORM128_F;
        }
    }
}

// node update: smem [0,32K) pk | [32K,34K) sh_as | [34K,40K) sh_av
__device__ __forceinline__ void node_update_body(
    int blk, const float* __restrict__ agg_s, const float* __restrict__ agg_v,
    const float* __restrict__ attr, const unsigned* __restrict__ Wupk,
    const float* __restrict__ sc_s, const float* __restrict__ sc_v,
    float* __restrict__ s, float* __restrict__ v, int N, char* smem) {
    unsigned* pk = (unsigned*)smem;
    float (*sh_as)[64]  = (float(*)[64])(smem + 32768);
    float (*sh_av)[192] = (float(*)[192])(smem + 32768 + 2048);
    int ln = threadIdx.x >> 5, w = threadIdx.x & 31;
    for (int i = threadIdx.x; i < 2048; i += 256)
        ((uint4*)pk)[i] = ((const uint4*)Wupk)[i];
    for (int g = 0; g < 2; g++) {
        int n = blk * 16 + g * 8 + ln;
        bool valid = n < N;
        __syncthreads();
        if (valid) {
            sh_as[ln][w] = agg_s[n * 64 + w];
            sh_as[ln][32 + w] = agg_s[n * 64 + 32 + w];
#pragma unroll
            for (int i = 0; i < 6; i++)
                sh_av[ln][w * 6 + i] = agg_v[(size_t)n * 192 + w * 6 + i];
        }
        __syncthreads();
        if (!valid) continue;
        float4 at = *(const float4*)(attr + n * 4);
        float acc_s = 0.f, a0 = 0.f, a1 = 0.f, a2 = 0.f;
        for (int u = 0; u < 64; u++) {
            float gs = sh_as[ln][u];
            float g0 = sh_av[ln][u * 3 + 0];
            float g1 = sh_av[ln][u * 3 + 1];
            float g2 = sh_av[ln][u * 3 + 2];
            uint4 pv = *(const uint4*)(pk + u * 128 + w * 4);
            float w20x = bf2f((unsigned short)pv.x), w21x = bf2f((unsigned short)(pv.x >> 16));
            float w20y = bf2f((unsigned short)pv.y), w21y = bf2f((unsigned short)(pv.y >> 16));
            float w20z = bf2f((unsigned short)pv.z), w21z = bf2f((unsigned short)(pv.z >> 16));
            float w20w = bf2f((unsigned short)pv.w), w21w = bf2f((unsigned short)(pv.w >> 16));
            float d0 = at.x * w20x + at.y * w20y + at.z * w20z + at.w * w20w;
            float d1 = at.x * w21x + at.y * w21y + at.z * w21z + at.w * w21w;
            acc_s += gs * d0;
            a0 += g0 * d1; a1 += g1 * d1; a2 += g2 * d1;
        }
        float os = acc_s * NORM256_F;
        float sn = C_S_F * sc_s[n * 32 + w] + C_X_F * os;
        float sig = 1.0f / (1.0f + __expf(-sn));
        s[n * 32 + w] += sn * sig;   // silu(sn)
        float ov0 = a0 * NORM256_F, ov1 = a1 * NORM256_F, ov2 = a2 * NORM256_F;
        v[n * 96 + w * 3 + 0] += (C_S_F * sc_v[n * 96 + w * 3 + 0] + C_X_F * ov0) * sig;
        v[n * 96 + w * 3 + 1] += (C_S_F * sc_v[n * 96 + w * 3 + 1] + C_X_F * ov1) * sig;
        v[n * 96 + w * 3 + 2] += (C_S_F * sc_v[n * 96 + w * 3 + 2] + C_X_F * ov2) * sig;
    }
}

// ---------------------------------------------------------------- mega kernels
__global__ __launch_bounds__(256) void mega1(
    int nInit, int nSetup,
    const float* __restrict__ x, float* __restrict__ s, float* __restrict__ v,
    const float* __restrict__ Wfc1g, const float* __restrict__ Wfc2,
    const float* __restrict__ Wsc0, const float* __restrict__ Wl10,
    const float* __restrict__ Wsc1, const float* __restrict__ Wl11,
    const float* __restrict__ Wl20, const float* __restrict__ Wl21,
    unsigned short* __restrict__ wfc1f, unsigned short* __restrict__ wfc2f,
    float* __restrict__ Wfp, unsigned* __restrict__ Wupk,
    const int* __restrict__ edst, int* __restrict__ cnt, int N, int E) {
    int b = blockIdx.x;
    if (b < nInit) { init_sv_body(b, x, s, v, N); return; }
    b -= nInit;
    if (b < nSetup) {
        setup_weights_body(b, Wfc1g, Wfc2, Wsc0, Wl10, Wsc1, Wl11, Wl20, Wl21,
                           wfc1f, wfc2f, Wfp, Wupk);
        return;
    }
    b -= nSetup;
    csr_count_body(b, edst, cnt, E);
}

__global__ void csr_scan(const int* __restrict__ cnt, int* __restrict__ off,
                         int* __restrict__ cursor, int N) {
    __shared__ int sums[256];
    int t = threadIdx.x;
    int chunk = (N + 255) / 256;
    int lo = t * chunk, hi = lo + chunk; if (hi > N) hi = N;
    int s = 0;
    for (int i = lo; i < hi; i++) s += cnt[i];
    sums[t] = s;
    __syncthreads();
    for (int d = 1; d < 256; d <<= 1) {
        int v = (t >= d) ? sums[t - d] : 0;
        __syncthreads();
        sums[t] += v;
        __syncthreads();
    }
    int run = (t == 0) ? 0 : sums[t - 1];
    for (int i = lo; i < hi; i++) {
        off[i] = run; cursor[i] = run;
        run += cnt[i];
    }
}

// csr_fill || fctp(layer0, both paths) || zero agg ping-pong buffers
__global__ __launch_bounds__(256, 4) void mega2(
    int nFill, int nF,
    const int* __restrict__ edst, const int* __restrict__ esrc,
    const float* __restrict__ edge_vec, int* __restrict__ cursor,
    float* __restrict__ vec_csr, int* __restrict__ slot_dst, int E,
    const float* __restrict__ s, const float* __restrict__ v,
    const float* __restrict__ attr, const float* __restrict__ Wfp,
    float* __restrict__ sc_s, float* __restrict__ sc_v,
    float* __restrict__ xsv, int N,
    float* __restrict__ zero_base, int nZeroF4) {
    __shared__ __align__(16) char smem[35840];
    int b = blockIdx.x;
    if (b < nFill) {
        csr_fill_body(b, edst, esrc, edge_vec, cursor, vec_csr, slot_dst, E);
        return;
    }
    b -= nFill;
    if (b < 2 * nF) {
        node_fctp_body(b % nF, b / nF, s, v, attr, Wfp, sc_s, sc_v, xsv, N, smem);
        return;
    }
    b -= 2 * nF;
    int i = b * 256 + threadIdx.x;
    if (i < nZeroF4) {
        float4 z = {0.f, 0.f, 0.f, 0.f};
        ((float4*)zero_base)[i] = z;
    }
}

// ---------------------------------------------------------------- msg kernel
// Fused edge-weight MFMA + message + hierarchical reduction.
// 128 CSR slots/block (dst-sorted -> contiguous node range, typ. ~5 nodes).
// Phase 3 flushes register partials into a per-block LDS accumulator table
// (ds_add_f32, conflict-free); write-out does ONE pass per node: plain
// coalesced store for interior nodes, global atomicAdd only for the <=2
// boundary nodes. Fallback to pure global atomics if range > ACC_CAP.
__global__ __launch_bounds__(256, 3) void msg_kernel(
    const float* __restrict__ vec_csr, const int* __restrict__ slot_dst,
    const int* __restrict__ off, const int* __restrict__ cnt,
    const unsigned short* __restrict__ wfc1f,
    const unsigned short* __restrict__ wfc2f,
    const float* __restrict__ xsv,
    float* __restrict__ agg_s, float* __restrict__ agg_v, int E) {
    __shared__ __align__(16) float sh_vec[128][4];      // y0,y1,y2,src-bits
    __shared__ float sh_len[128];
    __shared__ int   sh_dst[128];
    __shared__ __align__(16) unsigned sh_w[128 * 64];   // 32 KB packed bf16 pairs
    __shared__ __align__(16) float sh_acc[ACC_CAP * 256];  // 16 KB node partials
    short* sh_h = (short*)sh_w;                          // aliased: 128*HS = 18.4 KB

    int tid = threadIdx.x;
    int e0 = blockIdx.x * 128;

    if (tid < 128) {
        int e = e0 + tid;
        float ex = 0.f, ey = 0.f, ez = 0.f, srcb = 0.f;
        int dst = -1;
        if (e < E) {
            float4 vv = *(const float4*)(vec_csr + (size_t)e * 4);
            ex = vv.x; ey = vv.y; ez = vv.z; srcb = vv.w;
            dst = slot_dst[e];
        }
        float len = sqrtf(ex * ex + ey * ey + ez * ez);
        float rinv = SQRT3_F / (len + 1e-9f);
        sh_vec[tid][0] = ex * rinv;
        sh_vec[tid][1] = ey * rinv;
        sh_vec[tid][2] = ez * rinv;
        sh_vec[tid][3] = srcb;
        sh_len[tid] = len;
        sh_dst[tid] = dst;
    }
#pragma unroll
    for (int i = tid; i < ACC_CAP * 64; i += 256)
        ((float4*)sh_acc)[i] = float4{0.f, 0.f, 0.f, 0.f};
    __syncthreads();

    int wave = tid >> 6, lane = tid & 63;
    int m16 = lane & 15, quad = lane >> 4;

    {   // ---- phase 1 (MFMA): h = silu((emb @ Wfc1)/sqrt(10)) -> bf16 sh_h
        bf16x8 bw1[4];
#pragma unroll
        for (int nt = 0; nt < 4; nt++)
            bw1[nt] = *(const bf16x8*)(wfc1f + nt * 512 + lane * 8);
#pragma unroll
        for (int mt = 0; mt < 2; mt++) {
            int e = wave * 32 + mt * 16 + m16;
            float len = sh_len[e];
            float uu = 2.0f * (len * 0.25f - 1.0f);
            float cut = (uu > 0.0f) ? 0.0f
                      : ((uu < -1.0f) ? 1.0f : 0.5f * (1.0f - __cosf(PI_F * uu)));
            bf16x8 afr;
#pragma unroll
            for (int j = 0; j < 8; j++) {
                int k = quad * 8 + j;
                float val = 0.f;
                if (k < NBASIS) {
                    float d = (len - k * CSTEP_F) * 2.5f;
                    val = __expf(-d * d) * cut;
                }
                afr[j] = (short)f2bf(val);
            }
#pragma unroll
            for (int nt = 0; nt < 4; nt++) {
                f32x4 acc = {0.f, 0.f, 0.f, 0.f};
                acc = __builtin_amdgcn_mfma_f32_16x16x32_bf16(afr, bw1[nt], acc, 0, 0, 0);
#pragma unroll
                for (int r = 0; r < 4; r++) {
                    float a = acc[r] * INV_SQRT10_F;
                    float h = a / (1.0f + __expf(-a));
                    int er = wave * 32 + mt * 16 + quad * 4 + r;
                    sh_h[er * HS + nt * 16 + m16] = (short)f2bf(h);
                }
            }
        }
    }
    __syncthreads();

    {   // ---- phase 2 (MFMA): w = (h @ Wfc2)/8 -> packed bf16 pairs in sh_w
        bf16x8 afr[2][2];
#pragma unroll
        for (int mt = 0; mt < 2; mt++)
#pragma unroll
            for (int ks = 0; ks < 2; ks++) {
                int e = wave * 32 + mt * 16 + m16;
                afr[mt][ks] = *(const bf16x8*)(sh_h + e * HS + ks * 32 + quad * 8);
            }
        __syncthreads();   // all sh_h reads done -> safe to overwrite via sh_w
#pragma unroll
        for (int nt = 0; nt < 4; nt++) {
            bf16x8 bfr[2][2];
#pragma unroll
            for (int ng = 0; ng < 2; ng++)
#pragma unroll
                for (int ks = 0; ks < 2; ks++)
                    bfr[ng][ks] = *(const bf16x8*)(
                        wfc2f + (((ng * 4 + nt) * 2 + ks) * 64 + lane) * 8);
#pragma unroll
            for (int mt = 0; mt < 2; mt++) {
                f32x4 a0 = {0.f, 0.f, 0.f, 0.f};
                f32x4 a1 = {0.f, 0.f, 0.f, 0.f};
                a0 = __builtin_amdgcn_mfma_f32_16x16x32_bf16(afr[mt][0], bfr[0][0], a0, 0, 0, 0);
                a0 = __builtin_amdgcn_mfma_f32_16x16x32_bf16(afr[mt][1], bfr[0][1], a0, 0, 0, 0);
                a1 = __builtin_amdgcn_mfma_f32_16x16x32_bf16(afr[mt][0], bfr[1][0], a1, 0, 0, 0);
                a1 = __builtin_amdgcn_mfma_f32_16x16x32_bf16(afr[mt][1], bfr[1][1], a1, 0, 0, 0);
                int nidx = nt * 16 + m16;
#pragma unroll
                for (int r = 0; r < 4; r++) {
                    int le = wave * 32 + mt * 16 + quad * 4 + r;
                    unsigned lo = f2bf(a0[r] * 0.125f);
                    unsigned hi = f2bf(a1[r] * 0.125f);
                    sh_w[le * 64 + nidx] = lo | (hi << 16);
                }
            }
        }
    }
    __syncthreads();

    {   // ---- phase 3: messages + hierarchical segmented reduction
        int last = E - 1 - e0; if (last > 127) last = 127;
        int n_first = sh_dst[0];
        int n_last  = sh_dst[last];
        int range = n_last - n_first + 1;
        bool fast = (range <= ACC_CAP);

        int qw = tid >> 5;      // 0..7, each owns 16 contiguous slots
        int u  = tid & 31;
        float as0 = 0, as1 = 0;
        float av00 = 0, av01 = 0, av02 = 0, av10 = 0, av11 = 0, av12 = 0;
        int run = -1;

        auto flush = [&]() {
            if (run >= 0) {
                if (fast) {
                    float* a = sh_acc + (run - n_first) * 256;
                    atomicAdd(&a[u], as0);
                    atomicAdd(&a[32 + u], as1);
                    atomicAdd(&a[64 + u * 3 + 0], av00);
                    atomicAdd(&a[64 + u * 3 + 1], av01);
                    atomicAdd(&a[64 + u * 3 + 2], av02);
                    atomicAdd(&a[160 + u * 3 + 0], av10);
                    atomicAdd(&a[160 + u * 3 + 1], av11);
                    atomicAdd(&a[160 + u * 3 + 2], av12);
                } else {
                    atomicAdd(&agg_s[run * 64 + u],       as0 * INV_SQRTNN_F);
                    atomicAdd(&agg_s[run * 64 + 32 + u],  as1 * INV_SQRTNN_F);
                    float* av = agg_v + (size_t)run * 192;
                    atomicAdd(&av[u * 3 + 0],      av00 * INV_SQRTNN_F);
                    atomicAdd(&av[u * 3 + 1],      av01 * INV_SQRTNN_F);
                    atomicAdd(&av[u * 3 + 2],      av02 * INV_SQRTNN_F);
                    atomicAdd(&av[96 + u * 3 + 0], av10 * INV_SQRTNN_F);
                    atomicAdd(&av[96 + u * 3 + 1], av11 * INV_SQRTNN_F);
                    atomicAdd(&av[96 + u * 3 + 2], av12 * INV_SQRTNN_F);
                }
            }
            as0 = as1 = av00 = av01 = av02 = av10 = av11 = av12 = 0.f;
        };

        int base = qw * 16;
#pragma unroll
        for (int kk = 0; kk < 16; kk += 4) {
            float4 x4v[4];
            unsigned q0v[4], q1v[4];
            int dstv[4];
            float y0v[4], y1v[4], y2v[4];
#pragma unroll
            for (int t = 0; t < 4; t++) {
                int i = base + kk + t;
                dstv[t] = sh_dst[i];
                float4 sv = *(const float4*)&sh_vec[i][0];
                y0v[t] = sv.x; y1v[t] = sv.y; y2v[t] = sv.z;
                int src = __float_as_int(sv.w);
                x4v[t] = *(const float4*)(xsv + (size_t)src * 128 + u * 4);
                q0v[t] = sh_w[i * 64 + u];
                q1v[t] = sh_w[i * 64 + 32 + u];
            }
#pragma unroll
            for (int t = 0; t < 4; t++) {
                int dst = dstv[t];
                if (dst != run) { flush(); run = dst; }
                float wa = bf2f((unsigned short)q0v[t]), wc = bf2f((unsigned short)(q0v[t] >> 16));
                float wb = bf2f((unsigned short)q1v[t]), wd = bf2f((unsigned short)(q1v[t] >> 16));
                float4 x4 = x4v[t];
                as0 += wa * x4.w;
                as1 += wb * (y0v[t] * x4.x + y1v[t] * x4.y + y2v[t] * x4.z) * INV_SQRT3_F;
                float tt = wc * x4.w;
                av00 += tt * y0v[t];  av01 += tt * y1v[t];  av02 += tt * y2v[t];
                av10 += wd * x4.x; av11 += wd * x4.y; av12 += wd * x4.z;
            }
        }
        flush();
        __syncthreads();

        if (fast) {
            // write-out: one pass per node; plain store if interior, atomic if
            // the node's slot run extends past this block's [e0, e0+128) window.
            for (int li = 0; li < range; li++) {
                int n = n_first + li;
                int o = off[n], c = cnt[n];
                bool shared_node = (o < e0) || (o + c > e0 + 128);
                float val = sh_acc[li * 256 + tid] * INV_SQRTNN_F;
                if (tid < 64) {
                    float* dp = &agg_s[n * 64 + tid];
                    if (shared_node) atomicAdd(dp, val); else *dp = val;
                } else {
                    float* dp = &agg_v[(size_t)n * 192 + (tid - 64)];
                    if (shared_node) atomicAdd(dp, val); else *dp = val;
                }
            }
        }
    }
}

// ------------------------------- node update (layer l) + fctp (layer l+1)
__global__ __launch_bounds__(256, 4) void update_fctp(
    const float* __restrict__ agg_s, const float* __restrict__ agg_v,
    const float* __restrict__ attr, const unsigned* __restrict__ Wupk,
    float* __restrict__ sc_s, float* __restrict__ sc_v,
    float* __restrict__ s, float* __restrict__ v,
    const float* __restrict__ Wfp_next, float* __restrict__ xsv,
    int N, int do_fctp) {
    __shared__ __align__(16) char smem[40960];
    node_update_body(blockIdx.x, agg_s, agg_v, attr, Wupk, sc_s, sc_v, s, v, N, smem);
    if (do_fctp) {
        __syncthreads();   // pk/sh_as reads done; s,v global writes drained
        node_fctp_body(blockIdx.x, 0, s, v, attr, Wfp_next, sc_s, sc_v, xsv, N, smem);
        __syncthreads();   // w0/w1 reads done before path-1 reload
        node_fctp_body(blockIdx.x, 1, s, v, attr, Wfp_next, sc_s, sc_v, xsv, N, smem);
    }
}

// ---------------------------------------------------------------- readout
__global__ __launch_bounds__(256) void readout(
    const float* __restrict__ s, const float* __restrict__ attr,
    const float* __restrict__ Wread, const int* __restrict__ batch,
    float* __restrict__ out, int N, float pool_scale) {
    __shared__ float wr[2048];
    __shared__ float red[NGRAPH * 16];
    for (int i = threadIdx.x; i < 2048; i += 256) wr[i] = Wread[i];
    if (threadIdx.x < NGRAPH * 16) red[threadIdx.x] = 0.f;
    __syncthreads();
    int ln = threadIdx.x >> 4, w = threadIdx.x & 15;
    for (int g = 0; g < 4; g++) {
        int n = blockIdx.x * 64 + g * 16 + ln;
        if (n < N) {
            float4 at = *(const float4*)(attr + n * 4);
            float fa[4] = {at.x, at.y, at.z, at.w};
            float acc = 0.f;
            for (int u = 0; u < 32; u++) {
                float su = s[n * 32 + u];
                int base = u * 64 + w;
#pragma unroll
                for (int a = 0; a < 4; a++) acc += su * fa[a] * wr[base + a * 16];
            }
            atomicAdd(&red[batch[n] * 16 + w], acc);
        }
    }
    __syncthreads();
    if (threadIdx.x < NGRAPH * 16) {
        float val = red[threadIdx.x];
        if (val != 0.f)
            atomicAdd(&out[threadIdx.x], val * NORM128_F * pool_scale);
    }
}

// ---------------------------------------------------------------- launch
extern "C" void kernel_launch(void* const* d_in, const int* in_sizes, int n_in,
                              void* d_out, int out_size, void* d_ws, size_t ws_size,
                              hipStream_t stream) {
    const float* x        = (const float*)d_in[0];
    const float* nattr    = (const float*)d_in[1];
    const float* edge_vec = (const float*)d_in[2];
    const int*   batch    = (const int*)d_in[3];
    const int*   esrc     = (const int*)d_in[4];
    const int*   edst     = (const int*)d_in[5];
    const float* Wsc0  = (const float*)d_in[6];
    const float* Wsc1  = (const float*)d_in[7];
    const float* Wl10  = (const float*)d_in[8];
    const float* Wl11  = (const float*)d_in[9];
    const float* Wfc1  = (const float*)d_in[10];
    const float* Wfc2  = (const float*)d_in[11];
    const float* Wl20  = (const float*)d_in[12];
    const float* Wl21  = (const float*)d_in[13];
    const float* Wread = (const float*)d_in[14];

    int N = in_sizes[0] / (MUL * 4);
    int E = in_sizes[2] / 3;

    float* p = (float*)d_ws;
    float* vec_csr = p; p += (size_t)E * 4;     // {ex,ey,ez,src-bits}
    int* slot_dst = (int*)p; p += E;            // dst per CSR slot
    unsigned short* wfc1f = (unsigned short*)p; p += 2048;  // 4096 bf16 frags (2 layers)
    unsigned short* wfc2f = (unsigned short*)p; p += 8192;  // 16384 bf16 frags (2 layers)
    float* Wfp    = p; p += 32768;              // 2 layers x 4 matrices x 4096
    unsigned* Wupk = (unsigned*)p; p += 16384;  // 2 layers x 8192 packed pair dwords
    float* s_buf  = p; p += (size_t)N * 32;
    float* v_buf  = p; p += (size_t)N * 96;
    float* sc_s   = p; p += (size_t)N * 32;
    float* sc_v   = p; p += (size_t)N * 96;
    float* xsv    = p; p += (size_t)N * 128;    // {xv0,xv1,xv2,xs} per (n,u)
    float* aggA_s = p; p += (size_t)N * 64;     // ping-pong agg buffers, contiguous
    float* aggA_v = p; p += (size_t)N * 192;
    float* aggB_s = p; p += (size_t)N * 64;
    float* aggB_v = p; p += (size_t)N * 192;
    int* cnt     = (int*)p; p += N;
    int* off     = (int*)p; p += N;
    int* cursor  = (int*)p; p += N;

    hipMemsetAsync(d_out, 0, (size_t)out_size * sizeof(float), stream);
    hipMemsetAsync(cnt, 0, (size_t)N * sizeof(int), stream);

    int nInit  = (N * 128 + 255) / 256;
    int nSetup = 272;
    int nCount = (E + 255) / 256;
    mega1<<<nInit + nSetup + nCount, 256, 0, stream>>>(
        nInit, nSetup, x, s_buf, v_buf,
        Wfc1, Wfc2, Wsc0, Wl10, Wsc1, Wl11, Wl20, Wl21,
        wfc1f, wfc2f, Wfp, Wupk, edst, cnt, N, E);

    csr_scan<<<1, 256, 0, stream>>>(cnt, off, cursor, N);

    int nFill = (E + 255) / 256;
    int nF = (N + 15) / 16;
    int nZeroF4 = N * 128;                      // 2 x N*256 floats as float4
    int nZeroBlk = (nZeroF4 + 255) / 256;
    mega2<<<nFill + 2 * nF + nZeroBlk, 256, 0, stream>>>(
        nFill, nF, edst, esrc, edge_vec, cursor, vec_csr, slot_dst, E,
        s_buf, v_buf, nattr, Wfp, sc_s, sc_v, xsv, N, aggA_s, nZeroF4);

    int nE = (E + 127) / 128;

    // ---- layer 0
    msg_kernel<<<nE, 256, 0, stream>>>(
        vec_csr, slot_dst, off, cnt, wfc1f, wfc2f, xsv, aggA_s, aggA_v, E);
    update_fctp<<<nF, 256, 0, stream>>>(
        aggA_s, aggA_v, nattr, Wupk, sc_s, sc_v, s_buf, v_buf,
        Wfp + 16384, xsv, N, 1);

    // ---- layer 1
    msg_kernel<<<nE, 256, 0, stream>>>(
        vec_csr, slot_dst, off, cnt, wfc1f + 2048, wfc2f + 8192, xsv, aggB_s, aggB_v, E);
    update_fctp<<<nF, 256, 0, stream>>>(
        aggB_s, aggB_v, nattr, Wupk + 8192, sc_s, sc_v, s_buf, v_buf,
        (const float*)0, xsv, N, 0);

    float pool_scale = (float)(1.0 / sqrt((double)N / (double)NGRAPH));
    readout<<<(N + 63) / 64, 256, 0, stream>>>(
        s_buf, nattr, Wread, batch, (float*)d_out, N, pool_scale);
}